// Round 10
// baseline (5986.669 us; speedup 1.0000x reference)
//
#include <hip/hip_runtime.h>
#include <math.h>

#define BATCH 32
#define SEQ   512
#define IDIM  256
#define RDIM  2048
#define ODIM  256
#define LEAK  0.3f

#define SCAN_BLOCKS  256
#define SCAN_THREADS 512
#define ROWS_PER_BLK 8   // RDIM / SCAN_BLOCKS

typedef float f4 __attribute__((ext_vector_type(4)));

__device__ __forceinline__ unsigned ld_flag(const unsigned* p) {
    return __hip_atomic_load(p, __ATOMIC_RELAXED, __HIP_MEMORY_SCOPE_AGENT);
}
__device__ __forceinline__ void st_flag(unsigned* p, unsigned v) {
    __hip_atomic_store(p, v, __ATOMIC_RELAXED, __HIP_MEMORY_SCOPE_AGENT);
}

// ---------------------------------------------------------------------------
// init: copy initial state into states slot 0, zero flags region (1024 words:
// A flags [0..255], goA [256], goB [288], B flags [512..767])
// ---------------------------------------------------------------------------
__global__ void esn_init(const float* __restrict__ s0, float* __restrict__ states,
                         unsigned* __restrict__ flags) {
    int idx = blockIdx.x * blockDim.x + threadIdx.x;
    const int n4 = (BATCH * RDIM) / 4;
    if (idx < n4) {
        ((float4*)states)[idx] = ((const float4*)s0)[idx];
    }
    if (idx < 1024) flags[idx] = 0u;
}

// ---------------------------------------------------------------------------
// u_proj GEMM: up[m][r] = sum_i u[b][t][i] * Win[r][i] + bias[r],  m = t*32+b
// Written into states slots 1..512 (up[t] aliases states[t+1]; consumed by the
// finalize lane via sc1 read before the same lane overwrites it).
// ---------------------------------------------------------------------------
#define UP_THREADS 256
__global__ __launch_bounds__(UP_THREADS) void esn_uproj(
    const float* __restrict__ u,      // (B, T, I)
    const float* __restrict__ Win,    // (R, I)
    const float* __restrict__ bias,   // (R)
    float* __restrict__ up)           // (T*B, R) == states + B*R
{
    __shared__ float St[32][68];
    __shared__ float Wt[32][68];

    const int tid  = threadIdx.x;
    const int row0 = blockIdx.x * 64;   // m-tile (m = t*32+b)
    const int o0   = blockIdx.y * 64;   // r-tile

    const int lr = tid >> 3;
    const int lk = (tid & 7) * 4;
    const int tx = tid & 15;
    const int ty = tid >> 4;

    const int m0 = row0 + lr;
    const int m1 = row0 + 32 + lr;
    const float* u0 = u + ((size_t)(m0 & 31) * SEQ + (m0 >> 5)) * IDIM;
    const float* u1 = u + ((size_t)(m1 & 31) * SEQ + (m1 >> 5)) * IDIM;

    float acc[4][4] = {};

    for (int kt = 0; kt < IDIM; kt += 32) {
        float4 a0 = *(const float4*)(u0 + kt + lk);
        float4 a1 = *(const float4*)(u1 + kt + lk);
        float4 w0 = *(const float4*)(Win + (size_t)(o0 + lr)      * IDIM + kt + lk);
        float4 w1 = *(const float4*)(Win + (size_t)(o0 + 32 + lr) * IDIM + kt + lk);
        __syncthreads();
        float av0[4] = {a0.x, a0.y, a0.z, a0.w};
        float av1[4] = {a1.x, a1.y, a1.z, a1.w};
        float wv0[4] = {w0.x, w0.y, w0.z, w0.w};
        float wv1[4] = {w1.x, w1.y, w1.z, w1.w};
        #pragma unroll
        for (int j = 0; j < 4; ++j) {
            St[lk + j][lr]      = av0[j];
            St[lk + j][32 + lr] = av1[j];
            Wt[lk + j][lr]      = wv0[j];
            Wt[lk + j][32 + lr] = wv1[j];
        }
        __syncthreads();
        #pragma unroll
        for (int k = 0; k < 32; ++k) {
            float4 a4 = *(const float4*)(&St[k][4 * ty]);
            float4 b4 = *(const float4*)(&Wt[k][4 * tx]);
            float av[4] = {a4.x, a4.y, a4.z, a4.w};
            float bv[4] = {b4.x, b4.y, b4.z, b4.w};
            #pragma unroll
            for (int ri = 0; ri < 4; ++ri)
                #pragma unroll
                for (int oi = 0; oi < 4; ++oi)
                    acc[ri][oi] += av[ri] * bv[oi];
        }
    }

    float4 bs = *(const float4*)(bias + o0 + 4 * tx);
    float bsv[4] = {bs.x, bs.y, bs.z, bs.w};
    #pragma unroll
    for (int ri = 0; ri < 4; ++ri) {
        int row = row0 + 4 * ty + ri;
        float4 v;
        v.x = acc[ri][0] + bsv[0];
        v.y = acc[ri][1] + bsv[1];
        v.z = acc[ri][2] + bsv[2];
        v.w = acc[ri][3] + bsv[3];
        *(float4*)(up + (size_t)row * RDIM + o0 + 4 * tx) = v;
    }
}

// ===========================================================================
// Macro-expanded register file (round 9): NO local arrays -> plain VGPRs.
// ===========================================================================
#define DECL_A(r)  float A##r##0 = 0.0f, A##r##1 = 0.0f, A##r##2 = 0.0f, A##r##3 = 0.0f;
#define ZERO_A(r)  A##r##0 = 0.0f; A##r##1 = 0.0f; A##r##2 = 0.0f; A##r##3 = 0.0f;
#define DOT_ROW(r) { f4 w = *(const f4*)(wl + (r) * RDIM); \
    A##r##0 += w[0]*SC0[0] + w[1]*SC0[1] + w[2]*SC0[2] + w[3]*SC0[3]; \
    A##r##1 += w[0]*SC1[0] + w[1]*SC1[1] + w[2]*SC1[2] + w[3]*SC1[3]; \
    A##r##2 += w[0]*SC2[0] + w[1]*SC2[1] + w[2]*SC2[2] + w[3]*SC2[3]; \
    A##r##3 += w[0]*SC3[0] + w[1]*SC3[1] + w[2]*SC3[2] + w[3]*SC3[3]; }
#define RED12(x)   { x += __shfl_xor(x, 1, 64); x += __shfl_xor(x, 2, 64); }
#define RED_A(r)   RED12(A##r##0) RED12(A##r##1) RED12(A##r##2) RED12(A##r##3)
#define COMPACT(r) float V##r; { \
    float x01 = (q & 1) ? A##r##1 : A##r##0; \
    float x23 = (q & 1) ? A##r##3 : A##r##2; \
    float v   = (q & 2) ? x23 : x01; \
    v += __shfl_xor(v, 4, 64);  v += __shfl_xor(v, 8, 64); \
    v += __shfl_xor(v, 16, 64); v += __shfl_xor(v, 32, 64); \
    V##r = v; }

// ---------------------------------------------------------------------------
// persistent cooperative scan - TWO independent barrier domains.
// Batches never couple in the recurrence: group A = waves 0-3 (batches 0-15),
// group B = waves 4-7 (batches 16-31) are fully independent chains. Each SIMD
// hosts one wave of each group, so group B computes at full issue rate while
// group A's global barrier propagates, and vice versa (alternation enforced
// by LDS counters; phase offset seeded at t=0 by B waiting for local A).
// Per-group barrier = round-6 two-hop (per-block sc1 flag -> block0 aggregator
// -> go line -> 1 relay poller per block -> LDS broadcast). No __syncthreads
// in the step loop. Memory protocol unchanged (proven r3-r9): sc1 write-once
// per address, cached reads first-touched only after the group's barrier.
// ---------------------------------------------------------------------------
__global__ __launch_bounds__(SCAN_THREADS) void esn_scan(
    const float* __restrict__ W,      // (R, R)
    float* __restrict__ states,      // (T+1, B, R); slots 1..512 hold uproj
    unsigned* __restrict__ flags)    // A:[0..255] goA:[256] goB:[288] B:[512..767]
{
    __shared__ float Wl[ROWS_PER_BLK * RDIM];   // 64 KB
    __shared__ unsigned lsync[32];   // [0]=cntA [8]=cntB [16]=golA [24]=golB

    const int tid  = threadIdx.x;
    const int bid  = blockIdx.x;
    const int r0   = bid * ROWS_PER_BLK;

    if (tid < 32) lsync[tid] = 0u;

    // ---- stage W slice (contiguous 64 KB) into LDS ----
    {
        const float4* src = (const float4*)(W + (size_t)r0 * RDIM);
        float4* dst = (float4*)Wl;
        #pragma unroll
        for (int i = 0; i < (ROWS_PER_BLK * RDIM) / 4 / SCAN_THREADS; ++i)
            dst[i * SCAN_THREADS + tid] = src[i * SCAN_THREADS + tid];
    }

    const int wave = tid >> 6;           // 0..7
    const int lane = tid & 63;           // 64-way k-split
    const int grp  = wave >> 2;          // 0: batches 0-15, 1: batches 16-31
    const int b0   = wave * 4;           // batches b0..b0+3
    const int kb   = lane * 4;           // k base within each 256-chunk
    const int q    = lane & 3;

    const int bf = b0 + q;               // finalize batch (lanes<32)
    const int rr = lane >> 2;            // finalize row   (lanes<32)
    const size_t fin_off = (size_t)bf * RDIM + r0 + rr;

    unsigned* myflag = flags + (grp ? 512 : 0) + bid;
    unsigned* fbase  = flags + (grp ? 512 : 0);
    unsigned* go     = flags + (grp ? 288 : 256);
    volatile unsigned* cnt_mine  = (volatile unsigned*)&lsync[grp ? 8 : 0];
    volatile unsigned* cnt_other = (volatile unsigned*)&lsync[grp ? 0 : 8];
    volatile unsigned* gol       = (volatile unsigned*)&lsync[grp ? 24 : 16];
    const bool is_relay = (wave == (grp ? 4 : 0));
    const bool is_agg   = (bid == 0) && is_relay;

    // carry the finalize element's state in a register (slot 0 = s0)
    float so = 0.0f;
    if (lane < 32) so = states[fin_off];

    DECL_A(0) DECL_A(1) DECL_A(2) DECL_A(3)
    DECL_A(4) DECL_A(5) DECL_A(6) DECL_A(7)

    __syncthreads();   // Wl + lsync ready (last block-wide sync)

    for (int t = 0; t < SEQ; ++t) {
        const float* prev = states + (size_t)t * (BATCH * RDIM);
        float* next = states + (size_t)(t + 1) * (BATCH * RDIM);

        // ---- gates (LDS, broadcast reads, zero fabric traffic) ----
        // data gate: my group's global barrier released slot t
        while (*gol < (unsigned)t) __builtin_amdgcn_s_sleep(1);
        // alternation gate: other group locally done with its prior step
        {
            const unsigned alt = 4u * (unsigned)t + (grp ? 4u : 0u);
            while (*cnt_other < alt) __builtin_amdgcn_s_sleep(1);
        }
        asm volatile("" ::: "memory");

        // uproj for this step (slot t+1; sc1 non-allocating read, own lane)
        float up = 0.0f;
        if (lane < 32)
            up = __hip_atomic_load(&next[fin_off], __ATOMIC_RELAXED,
                                   __HIP_MEMORY_SCOPE_AGENT);

        ZERO_A(0) ZERO_A(1) ZERO_A(2) ZERO_A(3)
        ZERO_A(4) ZERO_A(5) ZERO_A(6) ZERO_A(7)

        // ---- recurrent dot: 8 chunks of 256 k, named regs + prefetch ----
        {
            const float* sb = prev + kb;
            f4 SC0 = *(const f4*)(sb + (size_t)(b0 + 0) * RDIM);
            f4 SC1 = *(const f4*)(sb + (size_t)(b0 + 1) * RDIM);
            f4 SC2 = *(const f4*)(sb + (size_t)(b0 + 2) * RDIM);
            f4 SC3 = *(const f4*)(sb + (size_t)(b0 + 3) * RDIM);

            #pragma unroll 1
            for (int c = 0; c < 8; ++c) {
                f4 SN0 = SC0, SN1 = SC1, SN2 = SC2, SN3 = SC3;
                if (c < 7) {
                    SN0 = *(const f4*)(sb + (size_t)(b0 + 0) * RDIM + (c + 1) * 256);
                    SN1 = *(const f4*)(sb + (size_t)(b0 + 1) * RDIM + (c + 1) * 256);
                    SN2 = *(const f4*)(sb + (size_t)(b0 + 2) * RDIM + (c + 1) * 256);
                    SN3 = *(const f4*)(sb + (size_t)(b0 + 3) * RDIM + (c + 1) * 256);
                }
                const float* wl = &Wl[c * 256 + kb];
                DOT_ROW(0) DOT_ROW(1) DOT_ROW(2) DOT_ROW(3)
                DOT_ROW(4) DOT_ROW(5) DOT_ROW(6) DOT_ROW(7)
                SC0 = SN0; SC1 = SN1; SC2 = SN2; SC3 = SN3;
            }
        }

        // ---- reduce over 64 lanes ----
        RED_A(0) RED_A(1) RED_A(2) RED_A(3)
        RED_A(4) RED_A(5) RED_A(6) RED_A(7)
        COMPACT(0) COMPACT(1) COMPACT(2) COMPACT(3)
        COMPACT(4) COMPACT(5) COMPACT(6) COMPACT(7)

        // ---- finalize: pre = dot + uproj; sc1 write-through store ----
        if (lane < 32) {
            float pre = V0;
            if (rr == 1) pre = V1;
            if (rr == 2) pre = V2;
            if (rr == 3) pre = V3;
            if (rr == 4) pre = V4;
            if (rr == 5) pre = V5;
            if (rr == 6) pre = V6;
            if (rr == 7) pre = V7;
            pre += up;
            float sn = (1.0f - LEAK) * so + LEAK * tanhf(pre);
            so = sn;   // register carry for step t+1
            __hip_atomic_store(&next[fin_off], sn,
                               __ATOMIC_RELAXED, __HIP_MEMORY_SCOPE_AGENT);
        }

        // ---- arrival: own stores acked, then LDS count; last wave -> flag
        asm volatile("s_waitcnt vmcnt(0)" ::: "memory");
        const unsigned tp = (unsigned)(t + 1);
        if (lane == 0) {
            unsigned old = atomicAdd((unsigned*)cnt_mine, 1u);
            if (old == 4u * tp - 1u) st_flag(myflag, tp);
        }

        // ---- per-group barrier: aggregate (block0) / relay go -> LDS ----
        if (is_agg) {
            for (;;) {
                unsigned f0 = ld_flag(&fbase[lane]);
                unsigned f1 = ld_flag(&fbase[64 + lane]);
                unsigned f2 = ld_flag(&fbase[128 + lane]);
                unsigned f3 = ld_flag(&fbase[192 + lane]);
                bool ok = (f0 >= tp) & (f1 >= tp) & (f2 >= tp) & (f3 >= tp);
                if (__all(ok)) break;
                __builtin_amdgcn_s_sleep(2);
            }
            asm volatile("" ::: "memory");
            if (lane == 0) { st_flag(go, tp); *gol = tp; }
        } else if (is_relay) {
            if (lane == 0) {
                while (ld_flag(go) < tp) __builtin_amdgcn_s_sleep(2);
                *gol = tp;
            }
        }
    }
}

// ---------------------------------------------------------------------------
// readout: out[b][t][o] = sum_r states[t+1][b][r] * w_ro[o][r] + b_ro[o]
// ---------------------------------------------------------------------------
#define RO_THREADS 256
__global__ __launch_bounds__(RO_THREADS) void esn_readout(
    const float* __restrict__ states,   // (T+1, B, R); rows (t*32+b) start at slot 1
    const float* __restrict__ w_ro,     // (O, R)
    const float* __restrict__ b_ro,     // (O)
    float* __restrict__ out)            // (B, T, O)
{
    __shared__ float St[32][68];
    __shared__ float Wt[32][68];

    const int tid  = threadIdx.x;
    const int rb   = blockIdx.x >> 2;
    const int ob   = blockIdx.x & 3;
    const int row0 = rb * 64;
    const int o0   = ob * 64;
    const float* S = states + (size_t)BATCH * RDIM;   // skip slot 0

    const int lr = tid >> 3;
    const int lk = (tid & 7) * 4;
    const int tx = tid & 15;
    const int ty = tid >> 4;

    float acc[4][4] = {};

    for (int kt = 0; kt < RDIM; kt += 32) {
        float4 a0 = *(const float4*)(S + (size_t)(row0 + lr)      * RDIM + kt + lk);
        float4 a1 = *(const float4*)(S + (size_t)(row0 + 32 + lr) * RDIM + kt + lk);
        float4 w0 = *(const float4*)(w_ro + (size_t)(o0 + lr)      * RDIM + kt + lk);
        float4 w1 = *(const float4*)(w_ro + (size_t)(o0 + 32 + lr) * RDIM + kt + lk);
        __syncthreads();
        float av0[4] = {a0.x, a0.y, a0.z, a0.w};
        float av1[4] = {a1.x, a1.y, a1.z, a1.w};
        float wv0[4] = {w0.x, w0.y, w0.z, w0.w};
        float wv1[4] = {w1.x, w1.y, w1.z, w1.w};
        #pragma unroll
        for (int j = 0; j < 4; ++j) {
            St[lk + j][lr]      = av0[j];
            St[lk + j][32 + lr] = av1[j];
            Wt[lk + j][lr]      = wv0[j];
            Wt[lk + j][32 + lr] = wv1[j];
        }
        __syncthreads();
        #pragma unroll
        for (int k = 0; k < 32; ++k) {
            float4 a4 = *(const float4*)(&St[k][4 * ty]);
            float4 b4 = *(const float4*)(&Wt[k][4 * tx]);
            float av[4] = {a4.x, a4.y, a4.z, a4.w};
            float bv[4] = {b4.x, b4.y, b4.z, b4.w};
            #pragma unroll
            for (int ri = 0; ri < 4; ++ri)
                #pragma unroll
                for (int oi = 0; oi < 4; ++oi)
                    acc[ri][oi] += av[ri] * bv[oi];
        }
    }

    float4 br = *(const float4*)(b_ro + o0 + 4 * tx);
    float brv[4] = {br.x, br.y, br.z, br.w};
    #pragma unroll
    for (int ri = 0; ri < 4; ++ri) {
        int row = row0 + 4 * ty + ri;
        int tt  = row >> 5;
        int bbx = row & 31;
        float4 v;
        v.x = acc[ri][0] + brv[0];
        v.y = acc[ri][1] + brv[1];
        v.z = acc[ri][2] + brv[2];
        v.w = acc[ri][3] + brv[3];
        *(float4*)(out + ((size_t)bbx * SEQ + tt) * ODIM + o0 + 4 * tx) = v;
    }
}

// ---------------------------------------------------------------------------
extern "C" void kernel_launch(void* const* d_in, const int* in_sizes, int n_in,
                              void* d_out, int out_size, void* d_ws, size_t ws_size,
                              hipStream_t stream) {
    const float* u    = (const float*)d_in[0];
    const float* s0   = (const float*)d_in[1];
    const float* Win  = (const float*)d_in[2];
    const float* W    = (const float*)d_in[3];
    const float* bias = (const float*)d_in[4];
    const float* w_ro = (const float*)d_in[5];
    const float* b_ro = (const float*)d_in[6];
    float* out = (float*)d_out;

    const size_t states_elems = (size_t)(SEQ + 1) * BATCH * RDIM;
    const size_t states_bytes = states_elems * sizeof(float);
    const size_t need = states_bytes + 4096;
    if (ws_size < need) return;   // visible failure rather than OOB writes

    float* states = (float*)d_ws;
    unsigned* flags = (unsigned*)((char*)d_ws + states_bytes);

    // slot 0 = initial state; flags = 0
    esn_init<<<dim3(64), dim3(256), 0, stream>>>(s0, states, flags);

    // slots 1..512 = u_proj[t] (+bias), aliasing states[t+1]
    esn_uproj<<<dim3((SEQ * BATCH) / 64, RDIM / 64), dim3(UP_THREADS), 0, stream>>>(
        u, Win, bias, states + (size_t)BATCH * RDIM);

    void* args[] = { (void*)&W, (void*)&states, (void*)&flags };
    hipLaunchCooperativeKernel((const void*)esn_scan,
                               dim3(SCAN_BLOCKS), dim3(SCAN_THREADS),
                               args, 0, stream);

    esn_readout<<<dim3((SEQ * BATCH / 64) * (ODIM / 64)), dim3(RO_THREADS), 0, stream>>>(
        states, w_ro, b_ro, out);
}

// Round 11
// 4820.079 us; speedup vs baseline: 1.2420x; 1.2420x over previous
//
#include <hip/hip_runtime.h>
#include <math.h>

#define BATCH 32
#define SEQ   512
#define IDIM  256
#define RDIM  2048
#define ODIM  256
#define LEAK  0.3f

#define SCAN_BLOCKS  256
#define SCAN_THREADS 512
#define ROWS_PER_BLK 8   // RDIM / SCAN_BLOCKS

typedef float f4 __attribute__((ext_vector_type(4)));

__device__ __forceinline__ unsigned ld_flag(const unsigned* p) {
    return __hip_atomic_load(p, __ATOMIC_RELAXED, __HIP_MEMORY_SCOPE_AGENT);
}
__device__ __forceinline__ void st_flag(unsigned* p, unsigned v) {
    __hip_atomic_store(p, v, __ATOMIC_RELAXED, __HIP_MEMORY_SCOPE_AGENT);
}

// ---------------------------------------------------------------------------
// init: copy initial state into states slot 0, zero flags region
// flags layout: [0..255] per-block step flags; [256 + j*16], j=0..7: go copies
// ---------------------------------------------------------------------------
__global__ void esn_init(const float* __restrict__ s0, float* __restrict__ states,
                         unsigned* __restrict__ flags) {
    int idx = blockIdx.x * blockDim.x + threadIdx.x;
    const int n4 = (BATCH * RDIM) / 4;
    if (idx < n4) {
        ((float4*)states)[idx] = ((const float4*)s0)[idx];
    }
    if (idx < 1024) flags[idx] = 0u;
}

// ---------------------------------------------------------------------------
// u_proj GEMM: up[m][r] = sum_i u[b][t][i] * Win[r][i] + bias[r],  m = t*32+b
// Written into states slots 1..512 (up[t] aliases states[t+1]; consumed by the
// finalize lane via sc1 read before the same lane overwrites it).
// ---------------------------------------------------------------------------
#define UP_THREADS 256
__global__ __launch_bounds__(UP_THREADS) void esn_uproj(
    const float* __restrict__ u,      // (B, T, I)
    const float* __restrict__ Win,    // (R, I)
    const float* __restrict__ bias,   // (R)
    float* __restrict__ up)           // (T*B, R) == states + B*R
{
    __shared__ float St[32][68];
    __shared__ float Wt[32][68];

    const int tid  = threadIdx.x;
    const int row0 = blockIdx.x * 64;   // m-tile (m = t*32+b)
    const int o0   = blockIdx.y * 64;   // r-tile

    const int lr = tid >> 3;
    const int lk = (tid & 7) * 4;
    const int tx = tid & 15;
    const int ty = tid >> 4;

    const int m0 = row0 + lr;
    const int m1 = row0 + 32 + lr;
    const float* u0 = u + ((size_t)(m0 & 31) * SEQ + (m0 >> 5)) * IDIM;
    const float* u1 = u + ((size_t)(m1 & 31) * SEQ + (m1 >> 5)) * IDIM;

    float acc[4][4] = {};

    for (int kt = 0; kt < IDIM; kt += 32) {
        float4 a0 = *(const float4*)(u0 + kt + lk);
        float4 a1 = *(const float4*)(u1 + kt + lk);
        float4 w0 = *(const float4*)(Win + (size_t)(o0 + lr)      * IDIM + kt + lk);
        float4 w1 = *(const float4*)(Win + (size_t)(o0 + 32 + lr) * IDIM + kt + lk);
        __syncthreads();
        float av0[4] = {a0.x, a0.y, a0.z, a0.w};
        float av1[4] = {a1.x, a1.y, a1.z, a1.w};
        float wv0[4] = {w0.x, w0.y, w0.z, w0.w};
        float wv1[4] = {w1.x, w1.y, w1.z, w1.w};
        #pragma unroll
        for (int j = 0; j < 4; ++j) {
            St[lk + j][lr]      = av0[j];
            St[lk + j][32 + lr] = av1[j];
            Wt[lk + j][lr]      = wv0[j];
            Wt[lk + j][32 + lr] = wv1[j];
        }
        __syncthreads();
        #pragma unroll
        for (int k = 0; k < 32; ++k) {
            float4 a4 = *(const float4*)(&St[k][4 * ty]);
            float4 b4 = *(const float4*)(&Wt[k][4 * tx]);
            float av[4] = {a4.x, a4.y, a4.z, a4.w};
            float bv[4] = {b4.x, b4.y, b4.z, b4.w};
            #pragma unroll
            for (int ri = 0; ri < 4; ++ri)
                #pragma unroll
                for (int oi = 0; oi < 4; ++oi)
                    acc[ri][oi] += av[ri] * bv[oi];
        }
    }

    float4 bs = *(const float4*)(bias + o0 + 4 * tx);
    float bsv[4] = {bs.x, bs.y, bs.z, bs.w};
    #pragma unroll
    for (int ri = 0; ri < 4; ++ri) {
        int row = row0 + 4 * ty + ri;
        float4 v;
        v.x = acc[ri][0] + bsv[0];
        v.y = acc[ri][1] + bsv[1];
        v.z = acc[ri][2] + bsv[2];
        v.w = acc[ri][3] + bsv[3];
        *(float4*)(up + (size_t)row * RDIM + o0 + 4 * tx) = v;
    }
}

// ===========================================================================
// Macro-expanded register file (round 9): NO local arrays -> plain VGPRs.
// ===========================================================================
#define DECL_A(r)  float A##r##0 = 0.0f, A##r##1 = 0.0f, A##r##2 = 0.0f, A##r##3 = 0.0f;
#define ZERO_A(r)  A##r##0 = 0.0f; A##r##1 = 0.0f; A##r##2 = 0.0f; A##r##3 = 0.0f;
#define DOT_ROW(r) { f4 w = *(const f4*)(wl + (r) * RDIM); \
    A##r##0 += w[0]*SC0[0] + w[1]*SC0[1] + w[2]*SC0[2] + w[3]*SC0[3]; \
    A##r##1 += w[0]*SC1[0] + w[1]*SC1[1] + w[2]*SC1[2] + w[3]*SC1[3]; \
    A##r##2 += w[0]*SC2[0] + w[1]*SC2[1] + w[2]*SC2[2] + w[3]*SC2[3]; \
    A##r##3 += w[0]*SC3[0] + w[1]*SC3[1] + w[2]*SC3[2] + w[3]*SC3[3]; }
#define RED12(x)   { x += __shfl_xor(x, 1, 64); x += __shfl_xor(x, 2, 64); }
#define RED_A(r)   RED12(A##r##0) RED12(A##r##1) RED12(A##r##2) RED12(A##r##3)
#define COMPACT(r) float V##r; { \
    float x01 = (q & 1) ? A##r##1 : A##r##0; \
    float x23 = (q & 1) ? A##r##3 : A##r##2; \
    float v   = (q & 2) ? x23 : x01; \
    v += __shfl_xor(v, 4, 64);  v += __shfl_xor(v, 8, 64); \
    v += __shfl_xor(v, 16, 64); v += __shfl_xor(v, 32, 64); \
    V##r = v; }

// ---------------------------------------------------------------------------
// persistent cooperative scan - round 9 compute (best measured), with the
// barrier's serial chain shortened:
//  - NO __syncthreads in the step loop. Arrival = per-wave vmcnt(0) drain +
//    one LDS atomicAdd; block's wave0-lane0 spins the LDS counter (monotone,
//    target 8*(t+1)) then sets the block's sc1 flag.
//  - Release = EVERY wave polls a go line directly (one wave-wide sc1 load)
//    and proceeds the instant it fires (no block-wide wake chain).
//  - go replicated x8 (aggregator lanes 0-7 store copies; block polls copy
//    bid&7) to avoid a 2048-pollers-one-line MALL hotspot.
// Memory protocol unchanged (proven r3-r9): sc1 write-once per address;
// cached reads first-touched only after the global release => never stale.
// ---------------------------------------------------------------------------
__global__ __launch_bounds__(SCAN_THREADS) void esn_scan(
    const float* __restrict__ W,      // (R, R)
    float* __restrict__ states,       // (T+1, B, R); slots 1..512 hold uproj
    unsigned* __restrict__ flags)     // [0..255] block flags; [256+j*16] go copies
{
    __shared__ float Wl[ROWS_PER_BLK * RDIM];   // 64 KB
    __shared__ unsigned lcnt;                    // block arrival counter

    const int tid  = threadIdx.x;
    const int bid  = blockIdx.x;
    const int r0   = bid * ROWS_PER_BLK;

    if (tid == 0) lcnt = 0u;

    // ---- stage W slice (contiguous 64 KB) into LDS ----
    {
        const float4* src = (const float4*)(W + (size_t)r0 * RDIM);
        float4* dst = (float4*)Wl;
        #pragma unroll
        for (int i = 0; i < (ROWS_PER_BLK * RDIM) / 4 / SCAN_THREADS; ++i)
            dst[i * SCAN_THREADS + tid] = src[i * SCAN_THREADS + tid];
    }

    const int wave = tid >> 6;           // 0..7
    const int lane = tid & 63;           // 64-way k-split
    const int b0   = wave * 4;           // batches b0..b0+3
    const int kb   = lane * 4;           // k base within each 256-chunk
    const int q    = lane & 3;

    const int bf = b0 + q;               // finalize batch (lanes<32)
    const int rr = lane >> 2;            // finalize row   (lanes<32)
    const size_t fin_off = (size_t)bf * RDIM + r0 + rr;

    unsigned* mygo = &flags[256 + (bid & 7) * 16];
    const bool is_agg = (bid == 0) && (wave == 0);

    // carry the finalize element's state in a register (slot 0 = s0)
    float so = 0.0f;
    if (lane < 32) so = states[fin_off];

    DECL_A(0) DECL_A(1) DECL_A(2) DECL_A(3)
    DECL_A(4) DECL_A(5) DECL_A(6) DECL_A(7)

    __syncthreads();   // Wl + lcnt ready (only block-wide sync in the kernel)

    for (int t = 0; t < SEQ; ++t) {
        const float* prev = states + (size_t)t * (BATCH * RDIM);
        float* next = states + (size_t)(t + 1) * (BATCH * RDIM);

        // uproj for this step (slot t+1; own lane's address, written only by
        // uproj kernel before the scan -> safe to read any time; sc1
        // non-allocating so the later overwrite can't be shadowed)
        float up = 0.0f;
        if (lane < 32)
            up = __hip_atomic_load(&next[fin_off], __ATOMIC_RELAXED,
                                   __HIP_MEMORY_SCOPE_AGENT);

        ZERO_A(0) ZERO_A(1) ZERO_A(2) ZERO_A(3)
        ZERO_A(4) ZERO_A(5) ZERO_A(6) ZERO_A(7)

        // ---- recurrent dot: 8 chunks of 256 k, named regs + prefetch ----
        {
            const float* sb = prev + kb;
            f4 SC0 = *(const f4*)(sb + (size_t)(b0 + 0) * RDIM);
            f4 SC1 = *(const f4*)(sb + (size_t)(b0 + 1) * RDIM);
            f4 SC2 = *(const f4*)(sb + (size_t)(b0 + 2) * RDIM);
            f4 SC3 = *(const f4*)(sb + (size_t)(b0 + 3) * RDIM);

            #pragma unroll 1
            for (int c = 0; c < 8; ++c) {
                f4 SN0 = SC0, SN1 = SC1, SN2 = SC2, SN3 = SC3;
                if (c < 7) {
                    SN0 = *(const f4*)(sb + (size_t)(b0 + 0) * RDIM + (c + 1) * 256);
                    SN1 = *(const f4*)(sb + (size_t)(b0 + 1) * RDIM + (c + 1) * 256);
                    SN2 = *(const f4*)(sb + (size_t)(b0 + 2) * RDIM + (c + 1) * 256);
                    SN3 = *(const f4*)(sb + (size_t)(b0 + 3) * RDIM + (c + 1) * 256);
                }
                const float* wl = &Wl[c * 256 + kb];
                DOT_ROW(0) DOT_ROW(1) DOT_ROW(2) DOT_ROW(3)
                DOT_ROW(4) DOT_ROW(5) DOT_ROW(6) DOT_ROW(7)
                SC0 = SN0; SC1 = SN1; SC2 = SN2; SC3 = SN3;
            }
        }

        // ---- reduce over 64 lanes ----
        RED_A(0) RED_A(1) RED_A(2) RED_A(3)
        RED_A(4) RED_A(5) RED_A(6) RED_A(7)
        COMPACT(0) COMPACT(1) COMPACT(2) COMPACT(3)
        COMPACT(4) COMPACT(5) COMPACT(6) COMPACT(7)

        // ---- finalize: pre = dot + uproj; sc1 write-through store ----
        if (lane < 32) {
            float pre = V0;
            if (rr == 1) pre = V1;
            if (rr == 2) pre = V2;
            if (rr == 3) pre = V3;
            if (rr == 4) pre = V4;
            if (rr == 5) pre = V5;
            if (rr == 6) pre = V6;
            if (rr == 7) pre = V7;
            pre += up;
            float sn = (1.0f - LEAK) * so + LEAK * tanhf(pre);
            so = sn;   // register carry for step t+1
            __hip_atomic_store(&next[fin_off], sn,
                               __ATOMIC_RELAXED, __HIP_MEMORY_SCOPE_AGENT);
        }

        // ---- arrival: own stores acked at coherent point, LDS count ----
        asm volatile("s_waitcnt vmcnt(0)" ::: "memory");
        const unsigned tp = (unsigned)(t + 1);
        if (lane == 0) __hip_atomic_fetch_add(&lcnt, 1u, __ATOMIC_RELAXED,
                                              __HIP_MEMORY_SCOPE_WORKGROUP);

        if (wave == 0) {
            // block's wave0: lane0 waits for all 8 waves, then sets flag
            if (lane == 0) {
                while (__hip_atomic_load(&lcnt, __ATOMIC_RELAXED,
                                         __HIP_MEMORY_SCOPE_WORKGROUP) < 8u * tp)
                    __builtin_amdgcn_s_sleep(1);
                st_flag(&flags[bid], tp);
            }
            if (is_agg) {
                // block0/wave0: aggregate all 256 flags, then fan out go x8
                for (;;) {
                    unsigned f0 = ld_flag(&flags[lane]);
                    unsigned f1 = ld_flag(&flags[64 + lane]);
                    unsigned f2 = ld_flag(&flags[128 + lane]);
                    unsigned f3 = ld_flag(&flags[192 + lane]);
                    bool ok = (f0 >= tp) & (f1 >= tp) & (f2 >= tp) & (f3 >= tp);
                    if (__all(ok)) break;
                    __builtin_amdgcn_s_sleep(1);
                }
                asm volatile("" ::: "memory");
                if (lane < 8) st_flag(&flags[256 + lane * 16], tp);
                asm volatile("s_waitcnt vmcnt(0)" ::: "memory");
                continue;   // aggregator doesn't need to poll go
            }
        }

        // ---- release: every wave polls its go copy directly ----
        while (ld_flag(mygo) < tp) __builtin_amdgcn_s_sleep(1);
        asm volatile("" ::: "memory");
    }
}

// ---------------------------------------------------------------------------
// readout: out[b][t][o] = sum_r states[t+1][b][r] * w_ro[o][r] + b_ro[o]
// ---------------------------------------------------------------------------
#define RO_THREADS 256
__global__ __launch_bounds__(RO_THREADS) void esn_readout(
    const float* __restrict__ states,   // (T+1, B, R); rows (t*32+b) start at slot 1
    const float* __restrict__ w_ro,     // (O, R)
    const float* __restrict__ b_ro,     // (O)
    float* __restrict__ out)            // (B, T, O)
{
    __shared__ float St[32][68];
    __shared__ float Wt[32][68];

    const int tid  = threadIdx.x;
    const int rb   = blockIdx.x >> 2;
    const int ob   = blockIdx.x & 3;
    const int row0 = rb * 64;
    const int o0   = ob * 64;
    const float* S = states + (size_t)BATCH * RDIM;   // skip slot 0

    const int lr = tid >> 3;
    const int lk = (tid & 7) * 4;
    const int tx = tid & 15;
    const int ty = tid >> 4;

    float acc[4][4] = {};

    for (int kt = 0; kt < RDIM; kt += 32) {
        float4 a0 = *(const float4*)(S + (size_t)(row0 + lr)      * RDIM + kt + lk);
        float4 a1 = *(const float4*)(S + (size_t)(row0 + 32 + lr) * RDIM + kt + lk);
        float4 w0 = *(const float4*)(w_ro + (size_t)(o0 + lr)      * RDIM + kt + lk);
        float4 w1 = *(const float4*)(w_ro + (size_t)(o0 + 32 + lr) * RDIM + kt + lk);
        __syncthreads();
        float av0[4] = {a0.x, a0.y, a0.z, a0.w};
        float av1[4] = {a1.x, a1.y, a1.z, a1.w};
        float wv0[4] = {w0.x, w0.y, w0.z, w0.w};
        float wv1[4] = {w1.x, w1.y, w1.z, w1.w};
        #pragma unroll
        for (int j = 0; j < 4; ++j) {
            St[lk + j][lr]      = av0[j];
            St[lk + j][32 + lr] = av1[j];
            Wt[lk + j][lr]      = wv0[j];
            Wt[lk + j][32 + lr] = wv1[j];
        }
        __syncthreads();
        #pragma unroll
        for (int k = 0; k < 32; ++k) {
            float4 a4 = *(const float4*)(&St[k][4 * ty]);
            float4 b4 = *(const float4*)(&Wt[k][4 * tx]);
            float av[4] = {a4.x, a4.y, a4.z, a4.w};
            float bv[4] = {b4.x, b4.y, b4.z, b4.w};
            #pragma unroll
            for (int ri = 0; ri < 4; ++ri)
                #pragma unroll
                for (int oi = 0; oi < 4; ++oi)
                    acc[ri][oi] += av[ri] * bv[oi];
        }
    }

    float4 br = *(const float4*)(b_ro + o0 + 4 * tx);
    float brv[4] = {br.x, br.y, br.z, br.w};
    #pragma unroll
    for (int ri = 0; ri < 4; ++ri) {
        int row = row0 + 4 * ty + ri;
        int tt  = row >> 5;
        int bbx = row & 31;
        float4 v;
        v.x = acc[ri][0] + brv[0];
        v.y = acc[ri][1] + brv[1];
        v.z = acc[ri][2] + brv[2];
        v.w = acc[ri][3] + brv[3];
        *(float4*)(out + ((size_t)bbx * SEQ + tt) * ODIM + o0 + 4 * tx) = v;
    }
}

// ---------------------------------------------------------------------------
extern "C" void kernel_launch(void* const* d_in, const int* in_sizes, int n_in,
                              void* d_out, int out_size, void* d_ws, size_t ws_size,
                              hipStream_t stream) {
    const float* u    = (const float*)d_in[0];
    const float* s0   = (const float*)d_in[1];
    const float* Win  = (const float*)d_in[2];
    const float* W    = (const float*)d_in[3];
    const float* bias = (const float*)d_in[4];
    const float* w_ro = (const float*)d_in[5];
    const float* b_ro = (const float*)d_in[6];
    float* out = (float*)d_out;

    const size_t states_elems = (size_t)(SEQ + 1) * BATCH * RDIM;
    const size_t states_bytes = states_elems * sizeof(float);
    const size_t need = states_bytes + 4096;
    if (ws_size < need) return;   // visible failure rather than OOB writes

    float* states = (float*)d_ws;
    unsigned* flags = (unsigned*)((char*)d_ws + states_bytes);

    // slot 0 = initial state; flags = 0
    esn_init<<<dim3(64), dim3(256), 0, stream>>>(s0, states, flags);

    // slots 1..512 = u_proj[t] (+bias), aliasing states[t+1]
    esn_uproj<<<dim3((SEQ * BATCH) / 64, RDIM / 64), dim3(UP_THREADS), 0, stream>>>(
        u, Win, bias, states + (size_t)BATCH * RDIM);

    void* args[] = { (void*)&W, (void*)&states, (void*)&flags };
    hipLaunchCooperativeKernel((const void*)esn_scan,
                               dim3(SCAN_BLOCKS), dim3(SCAN_THREADS),
                               args, 0, stream);

    esn_readout<<<dim3((SEQ * BATCH / 64) * (ODIM / 64)), dim3(RO_THREADS), 0, stream>>>(
        states, w_ro, b_ro, out);
}

// Round 12
// 4602.363 us; speedup vs baseline: 1.3008x; 1.0473x over previous
//
#include <hip/hip_runtime.h>
#include <math.h>

#define BATCH 32
#define SEQ   512
#define IDIM  256
#define RDIM  2048
#define ODIM  256
#define LEAK  0.3f

#define SCAN_BLOCKS  256
#define SCAN_THREADS 512
#define ROWS_PER_BLK 8   // RDIM / SCAN_BLOCKS

typedef float f4 __attribute__((ext_vector_type(4)));
typedef float f2 __attribute__((ext_vector_type(2)));

__device__ __forceinline__ unsigned ld_flag(const unsigned* p) {
    return __hip_atomic_load(p, __ATOMIC_RELAXED, __HIP_MEMORY_SCOPE_AGENT);
}
__device__ __forceinline__ void st_flag(unsigned* p, unsigned v) {
    __hip_atomic_store(p, v, __ATOMIC_RELAXED, __HIP_MEMORY_SCOPE_AGENT);
}

// ---------------------------------------------------------------------------
// init: copy initial state into states slot 0, zero flags region
// flags layout: [0..255] per-block step flags; [256 + j*16], j=0..7: go copies
// ---------------------------------------------------------------------------
__global__ void esn_init(const float* __restrict__ s0, float* __restrict__ states,
                         unsigned* __restrict__ flags) {
    int idx = blockIdx.x * blockDim.x + threadIdx.x;
    const int n4 = (BATCH * RDIM) / 4;
    if (idx < n4) {
        ((float4*)states)[idx] = ((const float4*)s0)[idx];
    }
    if (idx < 1024) flags[idx] = 0u;
}

// ---------------------------------------------------------------------------
// u_proj GEMM: up[m][r] = sum_i u[b][t][i] * Win[r][i] + bias[r],  m = t*32+b
// Written into states slots 1..512 (up[t] aliases states[t+1]; consumed by the
// finalize lane via sc1 read before the same lane overwrites it).
// ---------------------------------------------------------------------------
#define UP_THREADS 256
__global__ __launch_bounds__(UP_THREADS) void esn_uproj(
    const float* __restrict__ u,      // (B, T, I)
    const float* __restrict__ Win,    // (R, I)
    const float* __restrict__ bias,   // (R)
    float* __restrict__ up)           // (T*B, R) == states + B*R
{
    __shared__ float St[32][68];
    __shared__ float Wt[32][68];

    const int tid  = threadIdx.x;
    const int row0 = blockIdx.x * 64;   // m-tile (m = t*32+b)
    const int o0   = blockIdx.y * 64;   // r-tile

    const int lr = tid >> 3;
    const int lk = (tid & 7) * 4;
    const int tx = tid & 15;
    const int ty = tid >> 4;

    const int m0 = row0 + lr;
    const int m1 = row0 + 32 + lr;
    const float* u0 = u + ((size_t)(m0 & 31) * SEQ + (m0 >> 5)) * IDIM;
    const float* u1 = u + ((size_t)(m1 & 31) * SEQ + (m1 >> 5)) * IDIM;

    float acc[4][4] = {};

    for (int kt = 0; kt < IDIM; kt += 32) {
        float4 a0 = *(const float4*)(u0 + kt + lk);
        float4 a1 = *(const float4*)(u1 + kt + lk);
        float4 w0 = *(const float4*)(Win + (size_t)(o0 + lr)      * IDIM + kt + lk);
        float4 w1 = *(const float4*)(Win + (size_t)(o0 + 32 + lr) * IDIM + kt + lk);
        __syncthreads();
        float av0[4] = {a0.x, a0.y, a0.z, a0.w};
        float av1[4] = {a1.x, a1.y, a1.z, a1.w};
        float wv0[4] = {w0.x, w0.y, w0.z, w0.w};
        float wv1[4] = {w1.x, w1.y, w1.z, w1.w};
        #pragma unroll
        for (int j = 0; j < 4; ++j) {
            St[lk + j][lr]      = av0[j];
            St[lk + j][32 + lr] = av1[j];
            Wt[lk + j][lr]      = wv0[j];
            Wt[lk + j][32 + lr] = wv1[j];
        }
        __syncthreads();
        #pragma unroll
        for (int k = 0; k < 32; ++k) {
            float4 a4 = *(const float4*)(&St[k][4 * ty]);
            float4 b4 = *(const float4*)(&Wt[k][4 * tx]);
            float av[4] = {a4.x, a4.y, a4.z, a4.w};
            float bv[4] = {b4.x, b4.y, b4.z, b4.w};
            #pragma unroll
            for (int ri = 0; ri < 4; ++ri)
                #pragma unroll
                for (int oi = 0; oi < 4; ++oi)
                    acc[ri][oi] += av[ri] * bv[oi];
        }
    }

    float4 bs = *(const float4*)(bias + o0 + 4 * tx);
    float bsv[4] = {bs.x, bs.y, bs.z, bs.w};
    #pragma unroll
    for (int ri = 0; ri < 4; ++ri) {
        int row = row0 + 4 * ty + ri;
        float4 v;
        v.x = acc[ri][0] + bsv[0];
        v.y = acc[ri][1] + bsv[1];
        v.z = acc[ri][2] + bsv[2];
        v.w = acc[ri][3] + bsv[3];
        *(float4*)(up + (size_t)row * RDIM + o0 + 4 * tx) = v;
    }
}

// ===========================================================================
// Macro-expanded register file: NO local arrays (r9 lesson - arrays never get
// SROA'd here). Accumulators are f2 vectors so the dot uses v_pk_fma_f32
// (packed fp32, 2 FLOPs/inst on CDNA4) -> 512 pk_fma instead of 1024 fmac.
// ===========================================================================
#define LO2(v) __builtin_shufflevector(v, v, 0, 1)
#define HI2(v) __builtin_shufflevector(v, v, 2, 3)
#define DECL_A(r)  f2 A##r##0 = {0.f,0.f}, A##r##1 = {0.f,0.f}, \
                      A##r##2 = {0.f,0.f}, A##r##3 = {0.f,0.f};
#define ZERO_A(r)  A##r##0 = fz; A##r##1 = fz; A##r##2 = fz; A##r##3 = fz;
#define DOT_ROW(r) { f4 w = *(const f4*)(wl + (r) * RDIM); \
    f2 wlo = LO2(w), whi = HI2(w); \
    A##r##0 = __builtin_elementwise_fma(wlo, LO2(SC0), A##r##0); \
    A##r##0 = __builtin_elementwise_fma(whi, HI2(SC0), A##r##0); \
    A##r##1 = __builtin_elementwise_fma(wlo, LO2(SC1), A##r##1); \
    A##r##1 = __builtin_elementwise_fma(whi, HI2(SC1), A##r##1); \
    A##r##2 = __builtin_elementwise_fma(wlo, LO2(SC2), A##r##2); \
    A##r##2 = __builtin_elementwise_fma(whi, HI2(SC2), A##r##2); \
    A##r##3 = __builtin_elementwise_fma(wlo, LO2(SC3), A##r##3); \
    A##r##3 = __builtin_elementwise_fma(whi, HI2(SC3), A##r##3); }
// horizontal f2->scalar, then the proven cross-lane reduce
#define HADD_A(r)  float B##r##0 = A##r##0[0] + A##r##0[1]; \
                   float B##r##1 = A##r##1[0] + A##r##1[1]; \
                   float B##r##2 = A##r##2[0] + A##r##2[1]; \
                   float B##r##3 = A##r##3[0] + A##r##3[1];
#define RED12(x)   { x += __shfl_xor(x, 1, 64); x += __shfl_xor(x, 2, 64); }
#define RED_A(r)   RED12(B##r##0) RED12(B##r##1) RED12(B##r##2) RED12(B##r##3)
#define COMPACT(r) float V##r; { \
    float x01 = (q & 1) ? B##r##1 : B##r##0; \
    float x23 = (q & 1) ? B##r##3 : B##r##2; \
    float v   = (q & 2) ? x23 : x01; \
    v += __shfl_xor(v, 4, 64);  v += __shfl_xor(v, 8, 64); \
    v += __shfl_xor(v, 16, 64); v += __shfl_xor(v, 32, 64); \
    V##r = v; }

// ---------------------------------------------------------------------------
// persistent cooperative scan - round-11 structure (best measured: no
// __syncthreads in the loop, LDS arrival counter, block flag -> block0/wave0
// aggregator -> go replicated x8 -> every wave polls directly), with the dot
// converted to packed-fp32 accumulation.
// Memory protocol unchanged (proven r3-r11): sc1 write-once per address;
// cached reads first-touched only after the global release => never stale.
// ---------------------------------------------------------------------------
__global__ __launch_bounds__(SCAN_THREADS)
__attribute__((amdgpu_waves_per_eu(2, 2)))
void esn_scan(
    const float* __restrict__ W,      // (R, R)
    float* __restrict__ states,       // (T+1, B, R); slots 1..512 hold uproj
    unsigned* __restrict__ flags)     // [0..255] block flags; [256+j*16] go copies
{
    __shared__ float Wl[ROWS_PER_BLK * RDIM];   // 64 KB
    __shared__ unsigned lcnt;                    // block arrival counter

    const int tid  = threadIdx.x;
    const int bid  = blockIdx.x;
    const int r0   = bid * ROWS_PER_BLK;
    const f2 fz = {0.0f, 0.0f};

    if (tid == 0) lcnt = 0u;

    // ---- stage W slice (contiguous 64 KB) into LDS ----
    {
        const float4* src = (const float4*)(W + (size_t)r0 * RDIM);
        float4* dst = (float4*)Wl;
        #pragma unroll
        for (int i = 0; i < (ROWS_PER_BLK * RDIM) / 4 / SCAN_THREADS; ++i)
            dst[i * SCAN_THREADS + tid] = src[i * SCAN_THREADS + tid];
    }

    const int wave = tid >> 6;           // 0..7
    const int lane = tid & 63;           // 64-way k-split
    const int b0   = wave * 4;           // batches b0..b0+3
    const int kb   = lane * 4;           // k base within each 256-chunk
    const int q    = lane & 3;

    const int bf = b0 + q;               // finalize batch (lanes<32)
    const int rr = lane >> 2;            // finalize row   (lanes<32)
    const size_t fin_off = (size_t)bf * RDIM + r0 + rr;

    unsigned* mygo = &flags[256 + (bid & 7) * 16];
    const bool is_agg = (bid == 0) && (wave == 0);

    // carry the finalize element's state in a register (slot 0 = s0)
    float so = 0.0f;
    if (lane < 32) so = states[fin_off];

    DECL_A(0) DECL_A(1) DECL_A(2) DECL_A(3)
    DECL_A(4) DECL_A(5) DECL_A(6) DECL_A(7)

    __syncthreads();   // Wl + lcnt ready (only block-wide sync in the kernel)

    for (int t = 0; t < SEQ; ++t) {
        const float* prev = states + (size_t)t * (BATCH * RDIM);
        float* next = states + (size_t)(t + 1) * (BATCH * RDIM);

        // uproj for this step (slot t+1; own lane's address; sc1
        // non-allocating so the later overwrite can't be shadowed)
        float up = 0.0f;
        if (lane < 32)
            up = __hip_atomic_load(&next[fin_off], __ATOMIC_RELAXED,
                                   __HIP_MEMORY_SCOPE_AGENT);

        ZERO_A(0) ZERO_A(1) ZERO_A(2) ZERO_A(3)
        ZERO_A(4) ZERO_A(5) ZERO_A(6) ZERO_A(7)

        // ---- recurrent dot: 8 chunks of 256 k, named regs + prefetch ----
        {
            const float* sb = prev + kb;
            f4 SC0 = *(const f4*)(sb + (size_t)(b0 + 0) * RDIM);
            f4 SC1 = *(const f4*)(sb + (size_t)(b0 + 1) * RDIM);
            f4 SC2 = *(const f4*)(sb + (size_t)(b0 + 2) * RDIM);
            f4 SC3 = *(const f4*)(sb + (size_t)(b0 + 3) * RDIM);

            #pragma unroll 1
            for (int c = 0; c < 8; ++c) {
                f4 SN0 = SC0, SN1 = SC1, SN2 = SC2, SN3 = SC3;
                if (c < 7) {
                    SN0 = *(const f4*)(sb + (size_t)(b0 + 0) * RDIM + (c + 1) * 256);
                    SN1 = *(const f4*)(sb + (size_t)(b0 + 1) * RDIM + (c + 1) * 256);
                    SN2 = *(const f4*)(sb + (size_t)(b0 + 2) * RDIM + (c + 1) * 256);
                    SN3 = *(const f4*)(sb + (size_t)(b0 + 3) * RDIM + (c + 1) * 256);
                }
                const float* wl = &Wl[c * 256 + kb];
                DOT_ROW(0) DOT_ROW(1) DOT_ROW(2) DOT_ROW(3)
                DOT_ROW(4) DOT_ROW(5) DOT_ROW(6) DOT_ROW(7)
                SC0 = SN0; SC1 = SN1; SC2 = SN2; SC3 = SN3;
            }
        }

        // ---- reduce: horizontal f2, then cross-lane (proven r9) ----
        HADD_A(0) HADD_A(1) HADD_A(2) HADD_A(3)
        HADD_A(4) HADD_A(5) HADD_A(6) HADD_A(7)
        RED_A(0) RED_A(1) RED_A(2) RED_A(3)
        RED_A(4) RED_A(5) RED_A(6) RED_A(7)
        COMPACT(0) COMPACT(1) COMPACT(2) COMPACT(3)
        COMPACT(4) COMPACT(5) COMPACT(6) COMPACT(7)

        // ---- finalize: pre = dot + uproj; sc1 write-through store ----
        if (lane < 32) {
            float pre = V0;
            if (rr == 1) pre = V1;
            if (rr == 2) pre = V2;
            if (rr == 3) pre = V3;
            if (rr == 4) pre = V4;
            if (rr == 5) pre = V5;
            if (rr == 6) pre = V6;
            if (rr == 7) pre = V7;
            pre += up;
            float sn = (1.0f - LEAK) * so + LEAK * tanhf(pre);
            so = sn;   // register carry for step t+1
            __hip_atomic_store(&next[fin_off], sn,
                               __ATOMIC_RELAXED, __HIP_MEMORY_SCOPE_AGENT);
        }

        // ---- arrival: own stores acked at coherent point, LDS count ----
        asm volatile("s_waitcnt vmcnt(0)" ::: "memory");
        const unsigned tp = (unsigned)(t + 1);
        if (lane == 0) __hip_atomic_fetch_add(&lcnt, 1u, __ATOMIC_RELAXED,
                                              __HIP_MEMORY_SCOPE_WORKGROUP);

        if (wave == 0) {
            // block's wave0: lane0 waits for all 8 waves, then sets flag
            if (lane == 0) {
                while (__hip_atomic_load(&lcnt, __ATOMIC_RELAXED,
                                         __HIP_MEMORY_SCOPE_WORKGROUP) < 8u * tp)
                    __builtin_amdgcn_s_sleep(1);
                st_flag(&flags[bid], tp);
            }
            if (is_agg) {
                // block0/wave0: aggregate all 256 flags, then fan out go x8
                for (;;) {
                    unsigned f0 = ld_flag(&flags[lane]);
                    unsigned f1 = ld_flag(&flags[64 + lane]);
                    unsigned f2v = ld_flag(&flags[128 + lane]);
                    unsigned f3 = ld_flag(&flags[192 + lane]);
                    bool ok = (f0 >= tp) & (f1 >= tp) & (f2v >= tp) & (f3 >= tp);
                    if (__all(ok)) break;
                    __builtin_amdgcn_s_sleep(1);
                }
                asm volatile("" ::: "memory");
                if (lane < 8) st_flag(&flags[256 + lane * 16], tp);
                asm volatile("s_waitcnt vmcnt(0)" ::: "memory");
                continue;   // aggregator doesn't need to poll go
            }
        }

        // ---- release: every wave polls its go copy directly ----
        while (ld_flag(mygo) < tp) __builtin_amdgcn_s_sleep(1);
        asm volatile("" ::: "memory");
    }
}

// ---------------------------------------------------------------------------
// readout: out[b][t][o] = sum_r states[t+1][b][r] * w_ro[o][r] + b_ro[o]
// ---------------------------------------------------------------------------
#define RO_THREADS 256
__global__ __launch_bounds__(RO_THREADS) void esn_readout(
    const float* __restrict__ states,   // (T+1, B, R); rows (t*32+b) start at slot 1
    const float* __restrict__ w_ro,     // (O, R)
    const float* __restrict__ b_ro,     // (O)
    float* __restrict__ out)            // (B, T, O)
{
    __shared__ float St[32][68];
    __shared__ float Wt[32][68];

    const int tid  = threadIdx.x;
    const int rb   = blockIdx.x >> 2;
    const int ob   = blockIdx.x & 3;
    const int row0 = rb * 64;
    const int o0   = ob * 64;
    const float* S = states + (size_t)BATCH * RDIM;   // skip slot 0

    const int lr = tid >> 3;
    const int lk = (tid & 7) * 4;
    const int tx = tid & 15;
    const int ty = tid >> 4;

    float acc[4][4] = {};

    for (int kt = 0; kt < RDIM; kt += 32) {
        float4 a0 = *(const float4*)(S + (size_t)(row0 + lr)      * RDIM + kt + lk);
        float4 a1 = *(const float4*)(S + (size_t)(row0 + 32 + lr) * RDIM + kt + lk);
        float4 w0 = *(const float4*)(w_ro + (size_t)(o0 + lr)      * RDIM + kt + lk);
        float4 w1 = *(const float4*)(w_ro + (size_t)(o0 + 32 + lr) * RDIM + kt + lk);
        __syncthreads();
        float av0[4] = {a0.x, a0.y, a0.z, a0.w};
        float av1[4] = {a1.x, a1.y, a1.z, a1.w};
        float wv0[4] = {w0.x, w0.y, w0.z, w0.w};
        float wv1[4] = {w1.x, w1.y, w1.z, w1.w};
        #pragma unroll
        for (int j = 0; j < 4; ++j) {
            St[lk + j][lr]      = av0[j];
            St[lk + j][32 + lr] = av1[j];
            Wt[lk + j][lr]      = wv0[j];
            Wt[lk + j][32 + lr] = wv1[j];
        }
        __syncthreads();
        #pragma unroll
        for (int k = 0; k < 32; ++k) {
            float4 a4 = *(const float4*)(&St[k][4 * ty]);
            float4 b4 = *(const float4*)(&Wt[k][4 * tx]);
            float av[4] = {a4.x, a4.y, a4.z, a4.w};
            float bv[4] = {b4.x, b4.y, b4.z, b4.w};
            #pragma unroll
            for (int ri = 0; ri < 4; ++ri)
                #pragma unroll
                for (int oi = 0; oi < 4; ++oi)
                    acc[ri][oi] += av[ri] * bv[oi];
        }
    }

    float4 br = *(const float4*)(b_ro + o0 + 4 * tx);
    float brv[4] = {br.x, br.y, br.z, br.w};
    #pragma unroll
    for (int ri = 0; ri < 4; ++ri) {
        int row = row0 + 4 * ty + ri;
        int tt  = row >> 5;
        int bbx = row & 31;
        float4 v;
        v.x = acc[ri][0] + brv[0];
        v.y = acc[ri][1] + brv[1];
        v.z = acc[ri][2] + brv[2];
        v.w = acc[ri][3] + brv[3];
        *(float4*)(out + ((size_t)bbx * SEQ + tt) * ODIM + o0 + 4 * tx) = v;
    }
}

// ---------------------------------------------------------------------------
extern "C" void kernel_launch(void* const* d_in, const int* in_sizes, int n_in,
                              void* d_out, int out_size, void* d_ws, size_t ws_size,
                              hipStream_t stream) {
    const float* u    = (const float*)d_in[0];
    const float* s0   = (const float*)d_in[1];
    const float* Win  = (const float*)d_in[2];
    const float* W    = (const float*)d_in[3];
    const float* bias = (const float*)d_in[4];
    const float* w_ro = (const float*)d_in[5];
    const float* b_ro = (const float*)d_in[6];
    float* out = (float*)d_out;

    const size_t states_elems = (size_t)(SEQ + 1) * BATCH * RDIM;
    const size_t states_bytes = states_elems * sizeof(float);
    const size_t need = states_bytes + 4096;
    if (ws_size < need) return;   // visible failure rather than OOB writes

    float* states = (float*)d_ws;
    unsigned* flags = (unsigned*)((char*)d_ws + states_bytes);

    // slot 0 = initial state; flags = 0
    esn_init<<<dim3(64), dim3(256), 0, stream>>>(s0, states, flags);

    // slots 1..512 = u_proj[t] (+bias), aliasing states[t+1]
    esn_uproj<<<dim3((SEQ * BATCH) / 64, RDIM / 64), dim3(UP_THREADS), 0, stream>>>(
        u, Win, bias, states + (size_t)BATCH * RDIM);

    void* args[] = { (void*)&W, (void*)&states, (void*)&flags };
    hipLaunchCooperativeKernel((const void*)esn_scan,
                               dim3(SCAN_BLOCKS), dim3(SCAN_THREADS),
                               args, 0, stream);

    esn_readout<<<dim3((SEQ * BATCH / 64) * (ODIM / 64)), dim3(RO_THREADS), 0, stream>>>(
        states, w_ro, b_ro, out);
}